// Round 4
// baseline (238.864 us; speedup 1.0000x reference)
//
#include <hip/hip_runtime.h>

// LIF scan, T=8, N=4M fp32. 268 MB logical traffic (134 R + 134 W); fills in
// this trace hit 6.7 TB/s, m13 float4 copy (same R/W mix) 6.29 -> ~43 us ideal
// kernel. Bench floor: 2x 512-MiB poison fills ~160 us; kernel ~64 us = 4.2 TB/s.
// Ladder: R1-R4 capped 2.2 TB/s (cache-allocate reads) -> NT loads fixed (R5).
// R6/R8/R9 burst depth / pipeline / store policy / TLB chunking all neutral.
// R10/R11 wave<->timestep LDS-DMA restructure (single sequential stream per
// wave, double-buffered, counted vmcnt): NEUTRAL ~64 us => stream geometry
// falsified. R12 flipped loads nt->cached: FAILED post-timing (absmax 1.0) --
// RACE in my vmcnt discipline, not the cache policy: wait_vmcnt<8> counted 4
// NT stores in the window, assuming mixed load/store in-order vmcnt
// retirement. Only LOAD-LOAD in-order is proven (m218 8-phase template counts
// loads only). Stores retiring out-of-order let vmcnt hit 8 with tile-k loads
// still in flight -> stale LDS reads. R11's pass was luck.
// R13: same structure, cached loads retained (the R12 A/B), store-agnostic
// waits: wait_vmcnt<4> every main-loop iter (4 newest VMEM = just-issued
// prefetch LOADS; load-load in-order => tile-k loads done; stores only
// inflate the count = conservative). Final iter drains vmcnt(0).

#define LIF_THRESH 0.5f
#define LIF_BETA   0.25f
#define LIF_T      8
#define BLOCK      512            // 8 waves; wave w <-> time-stream t=w
#define TILE_W     256            // v4f columns per tile (32 KiB x-slab)
#define TILES      8              // tiles per block -> block owns 2048 v4f cols

typedef float v4f __attribute__((ext_vector_type(4)));
typedef float v2f __attribute__((ext_vector_type(2)));

template <int N>
__device__ __forceinline__ void wait_vmcnt() {
    asm volatile("s_waitcnt vmcnt(%0)" ::"n"(N) : "memory");
}
__device__ __forceinline__ void wait_lgkmcnt0() {
    asm volatile("s_waitcnt lgkmcnt(0)" ::: "memory");
}
__device__ __forceinline__ void barrier_fenced() {
    // s_barrier that is ALSO a compiler memory fence: no LDS op may be
    // scheduled across it (the builtin alone is not a memory barrier).
    asm volatile("s_barrier" ::: "memory");
}

__global__ __launch_bounds__(BLOCK) void lif_kernel(const v4f* __restrict__ x,
                                                    v4f* __restrict__ out,
                                                    int n4) {
    __shared__ v4f xs[2][LIF_T][TILE_W];   // 2 x 32 KiB double buffer

    const int wave = threadIdx.x >> 6;
    const int lane = threadIdx.x & 63;
    const size_t col0  = (size_t)blockIdx.x * (TILE_W * TILES);
    const size_t gbase = (size_t)wave * (size_t)n4 + col0;   // stream t = wave

    // Stage one tile into buf: per wave, 4x global_load_lds_dwordx4.
    // aux=0: CACHED reads (the R12/R13 variable). LDS dst is wave-uniform
    // base + lane*16 (linear, m104 OK); global src per-lane sequential.
#define STAGE(tile, buf)                                                       \
    {                                                                          \
        _Pragma("unroll")                                                      \
        for (int i = 0; i < TILE_W / 64; ++i) {                                \
            __builtin_amdgcn_global_load_lds(                                  \
                (const __attribute__((address_space(1))) void*)                \
                    (&x[gbase + (size_t)(tile)*TILE_W + i * 64 + lane]),       \
                (__attribute__((address_space(3))) void*)                      \
                    (&xs[buf][wave][i * 64]),                                  \
                16, 0, 0 /* cached */);                                        \
        }                                                                      \
    }

    STAGE(0, 0);

#pragma unroll
    for (int k = 0; k < TILES; ++k) {
        const int buf = k & 1;

        // Prefetch tile k+1 into the other buffer before consuming tile k.
        // Safe vs iter k-1: this wave's DMA touches only its OWN row of
        // buf^1, whose store ds_reads completed (data dep through the store
        // operands) before the stores that precede this point in program
        // order.
        if (k + 1 < TILES) STAGE(k + 1, buf ^ 1);

        // Store-agnostic wait for OWN tile-k loads. Main loop: the 4 newest
        // VMEM ops are the prefetch LOADS just issued; load-load retirement
        // is in-order, so vmcnt<=4 proves every older load (tile k) retired.
        // Outstanding stores only inflate the count (conservative). Last
        // iter has no prefetch (newest = stores) -> counted argument breaks
        // -> full drain once.
        if (k + 1 < TILES) wait_vmcnt<4>();
        else               wait_vmcnt<0>();
        barrier_fenced();   // all 8 waves' slabs of tile k now resident

        // Compute: thread ci owns float2-column ci; full t-scan in LDS.
        // Spikes overwrite x in place (same thread, same address, rd->wr).
        {
            const int ci = threadIdx.x;
            float m0 = 0.f, m1 = 0.f;
#pragma unroll
            for (int t = 0; t < LIF_T; ++t) {
                v2f xv = ((const v2f*)xs[buf][t])[ci];
                m0 = m0 * LIF_BETA + xv.x;
                m1 = m1 * LIF_BETA + xv.y;
                v2f s;
                s.x = (m0 >= LIF_THRESH) ? 1.f : 0.f;
                s.y = (m1 >= LIF_THRESH) ? 1.f : 0.f;
                m0 = (m0 >= LIF_THRESH) ? 0.f : m0;
                m1 = (m1 >= LIF_THRESH) ? 0.f : m1;
                ((v2f*)xs[buf][t])[ci] = s;
            }
        }

        // Spikes in row t were written by threads of ALL waves -> drain own
        // ds_writes, then barrier, before cross-wave store reads.
        wait_lgkmcnt0();
        __builtin_amdgcn_sched_barrier(0);   // rule-18 insurance
        barrier_fenced();

        // Store: wave w streams spikes of out[t=w] -- one sequential stream.
#pragma unroll
        for (int i = 0; i < TILE_W / 64; ++i) {
            v4f s = xs[buf][wave][i * 64 + lane];
            __builtin_nontemporal_store(
                s, &out[gbase + (size_t)k * TILE_W + i * 64 + lane]);
        }
        // No barrier here: next iter's DMA into buf^1 only touches the
        // issuing wave's own row, and its own store ds_reads completed
        // before those stores issued (data dependency).
    }
#undef STAGE
}

extern "C" void kernel_launch(void* const* d_in, const int* in_sizes, int n_in,
                              void* d_out, int out_size, void* d_ws, size_t ws_size,
                              hipStream_t stream) {
    const v4f* x = (const v4f*)d_in[0];
    v4f* out = (v4f*)d_out;

    long long total = in_sizes[0];
    int n = (int)(total / LIF_T);   // 4,194,304 floats per timestep
    int n4 = n / 4;                 // 1,048,576 v4f columns per timestep

    dim3 block(BLOCK);
    dim3 grid(n4 / (TILE_W * TILES));   // 512 blocks -> 2/CU, 16 waves/CU
    lif_kernel<<<grid, block, 0, stream>>>(x, out, n4);
}

// Round 5
// 227.311 us; speedup vs baseline: 1.0508x; 1.0508x over previous
//
#include <hip/hip_runtime.h>

// LIF scan, T=8, N=4M fp32. 268 MB logical (134 R + 134 W); fills in-trace
// 6.55-6.73 TB/s; m13 float4 copy 6.29 -> ~43 us ideal. Bench floor: 2x 512MiB
// poison fills ~160 us; R9 kernel ~63 us = 4.2 TB/s.
// Ladder: R1-R4 cached reads 2.2 TB/s; NT loads -> 3.4 (R5), chunking -> 4.2
// (R9). R6/R8 burst/store-policy neutral (in NT regime). R10/R11 wave<->t LDS
// restructure (1 sequential stream/wave): NEUTRAL 4.2 => stream geometry
// falsified. R12 cached DMA loads: RACE (counted stores in vmcnt window);
// R13 fixed waits: PASS but 84 us, and FETCH=67MB proved HALF the reads were
// L3-hits yet slower => cached-allocate PATH is the cap, not HBM bytes. Cause:
// t-streams are 16MiB apart = 4x XCD-L2 -> all streams of all blocks alias one
// L2 index window. Structural; cached reads unfixable -> NT is right.
// R14 theory: R9/R11/R13 all hold ~64KB/CU in flight and all tie at 4.2 =>
// outstanding-bytes/CU is the controlling variable (loaded latency >> 900cy
// under queueing; fills run 32 churning waves/CU). Quadruple MLP: 16 waves/CU
// (grid 1024) x depth-3 prefetch (~16KB/wave) ~= 256KB/CU. Register-only
// structure (compiler-managed waitcnt, race-free), fully static buffer
// indices (rule 20).

#define LIF_THRESH 0.5f
#define LIF_BETA   0.25f
#define LIF_T      8
#define BLOCK      256
#define JITER      4
#define DEPTH      3

typedef float v4f __attribute__((ext_vector_type(4)));

__global__ __launch_bounds__(BLOCK, 4) void lif_kernel(const v4f* __restrict__ x,
                                                       v4f* __restrict__ out,
                                                       int n4) {
    // Block b owns contiguous columns [b*BLOCK*JITER, (b+1)*BLOCK*JITER).
    const int base = blockIdx.x * (BLOCK * JITER) + threadIdx.x;

    v4f buf[DEPTH][LIF_T];   // 96 VGPR; all indices compile-time after unroll

    // Prologue: chunks 0 and 1 in flight (nt: read-once streaming, the R5 win).
#pragma unroll
    for (int t = 0; t < LIF_T; ++t)
        buf[0][t] = __builtin_nontemporal_load(&x[(size_t)t * n4 + base]);
#pragma unroll
    for (int t = 0; t < LIF_T; ++t)
        buf[1][t] = __builtin_nontemporal_load(&x[(size_t)t * n4 + base + BLOCK]);

#pragma unroll
    for (int j = 0; j < JITER; ++j) {
        const int c = base + j * BLOCK;

        // Depth-3: issue chunk j+2 before consuming chunk j -> ~16KB/wave
        // outstanding through the whole compute+store phase.
        if (j + 2 < JITER) {
            const int cn = c + 2 * BLOCK;
#pragma unroll
            for (int t = 0; t < LIF_T; ++t)
                buf[(j + 2) % DEPTH][t] =
                    __builtin_nontemporal_load(&x[(size_t)t * n4 + cn]);
        }

        float m0 = 0.f, m1 = 0.f, m2 = 0.f, m3 = 0.f;
#pragma unroll
        for (int t = 0; t < LIF_T; ++t) {
            v4f xt = buf[j % DEPTH][t];   // j static -> register, no scratch
            m0 = m0 * LIF_BETA + xt.x;
            m1 = m1 * LIF_BETA + xt.y;
            m2 = m2 * LIF_BETA + xt.z;
            m3 = m3 * LIF_BETA + xt.w;

            v4f s;
            s.x = (m0 >= LIF_THRESH) ? 1.f : 0.f;
            s.y = (m1 >= LIF_THRESH) ? 1.f : 0.f;
            s.z = (m2 >= LIF_THRESH) ? 1.f : 0.f;
            s.w = (m3 >= LIF_THRESH) ? 1.f : 0.f;

            m0 = (m0 >= LIF_THRESH) ? 0.f : m0;
            m1 = (m1 >= LIF_THRESH) ? 0.f : m1;
            m2 = (m2 >= LIF_THRESH) ? 0.f : m2;
            m3 = (m3 >= LIF_THRESH) ? 0.f : m3;

            __builtin_nontemporal_store(s, &out[(size_t)t * n4 + c]);
        }
    }
}

extern "C" void kernel_launch(void* const* d_in, const int* in_sizes, int n_in,
                              void* d_out, int out_size, void* d_ws, size_t ws_size,
                              hipStream_t stream) {
    const v4f* x = (const v4f*)d_in[0];
    v4f* out = (v4f*)d_out;

    long long total = in_sizes[0];
    int n = (int)(total / LIF_T);   // 4,194,304 floats per timestep
    int n4 = n / 4;                 // 1,048,576 v4f columns per timestep

    dim3 block(BLOCK);
    dim3 grid(n4 / (BLOCK * JITER));   // 1024 blocks -> 4/CU, 16 waves/CU
    lif_kernel<<<grid, block, 0, stream>>>(x, out, n4);
}

// Round 6
// 226.489 us; speedup vs baseline: 1.0546x; 1.0036x over previous
//
#include <hip/hip_runtime.h>

// LIF scan, T=8, N=4M fp32. 268 MB logical (134 R + 134 W); fills in-trace
// 6.6-6.7 TB/s, m13 float4 copy 6.29 -> ~43 us ideal. Bench floor: 2x 512MiB
// poison fills ~160 us; best kernel (R9/R14) ~63-67 us = 4.2 TB/s.
// Ladder: cached reads 2.2 (R1-R4); nt loads 3.4 (R5); chunking 4.2 (R9).
// Neutral: burst depth, store policy, TLB chunking (R6-R9), stream geometry
// (R10/R11 LDS-DMA, 1 seq stream/wave), MLP 64->256KB/CU (R14). R12 raced
// (counted stores in vmcnt window -> only load-load retirement is in-order);
// R13 (cached DMA, safe waits) 84 us with FETCH=67MB: half the reads L3-hit
// yet SLOWER -> byte count isn't the limiter, the allocate PATH is.
// R15 theory: nt is a replacement HINT, not a bypass -- nt reads still transit
// the L2 set-indexed lookup/fill pipeline. All 8 t-streams are 16 MiB apart
// (4x the 4MiB XCD-L2 span) -> every concurrent read aliases one set window;
// 4.2 TB/s = contended-set bandwidth. Copy stripes sets evenly -> 6.3.
// Fix: sc1 (device-scope) on the load = skip L2 allocate entirely; L3 is
// memory-side and still serves. Needs inline asm (builtin can't emit sc1;
// volatile serializes). Waits: store-agnostic rule -- vmcnt(8) is safe iff
// the 8 newest VMEM ops are loads (load-load in-order retirement; an older
// outstanding load forces >=9); vmcnt(0) last chunk; sched_barrier(0) after
// each wait (rule 18). Parity-named buffers, zero rotation copies (a cur=nxt
// v_mov would read unlanded asm-load dests).

#define LIF_THRESH 0.5f
#define LIF_BETA   0.25f
#define LIF_T      8
#define BLOCK      256
#define JITER      8

typedef float v4f __attribute__((ext_vector_type(4)));

__global__ __launch_bounds__(BLOCK) void lif_kernel(const v4f* __restrict__ x,
                                                    v4f* __restrict__ out,
                                                    int n4) {
    // Block b owns contiguous columns [b*BLOCK*JITER, (b+1)*BLOCK*JITER).
    const int base = blockIdx.x * (BLOCK * JITER) + threadIdx.x;

    v4f bufA[LIF_T], bufB[LIF_T];   // depth-2, parity-named (static indices)

    // Prologue: chunk 0 -> bufA, sc1+nt reads (L2-bypass streaming).
#pragma unroll
    for (int t = 0; t < LIF_T; ++t) {
        const v4f* p = &x[(size_t)t * n4 + base];
        asm volatile("global_load_dwordx4 %0, %1, off sc1 nt"
                     : "=&v"(bufA[t]) : "v"(p) : "memory");
    }

    // One pipeline step. CUR holds chunk j (loads issued last step); NXT
    // receives chunk j+1. Membrane state is per-column -> resets every chunk.
#define STEP(j, CUR, NXT, ISLAST)                                              \
    {                                                                          \
        const int c = base + (j) * BLOCK;                                      \
        if (!(ISLAST)) {                                                       \
            _Pragma("unroll")                                                  \
            for (int t = 0; t < LIF_T; ++t) {                                  \
                const v4f* p = &x[(size_t)t * n4 + c + BLOCK];                 \
                asm volatile("global_load_dwordx4 %0, %1, off sc1 nt"          \
                             : "=&v"(NXT[t]) : "v"(p) : "memory");             \
            }                                                                  \
            /* 8 newest VMEM = the loads just issued; older chunk-j load      \
               outstanding would force vmcnt>=9 (load-load in-order). Stores  \
               only inflate the count = conservative. */                       \
            asm volatile("s_waitcnt vmcnt(8)" ::: "memory");                   \
        } else {                                                               \
            /* newest ops are stores -> counted argument breaks -> drain. */   \
            asm volatile("s_waitcnt vmcnt(0)" ::: "memory");                   \
        }                                                                      \
        __builtin_amdgcn_sched_barrier(0); /* rule 18: pin consumers below */  \
        float m0 = 0.f, m1 = 0.f, m2 = 0.f, m3 = 0.f;                          \
        _Pragma("unroll")                                                      \
        for (int t = 0; t < LIF_T; ++t) {                                      \
            v4f xt = CUR[t];                                                   \
            m0 = m0 * LIF_BETA + xt.x;                                         \
            m1 = m1 * LIF_BETA + xt.y;                                         \
            m2 = m2 * LIF_BETA + xt.z;                                         \
            m3 = m3 * LIF_BETA + xt.w;                                         \
            v4f s;                                                             \
            s.x = (m0 >= LIF_THRESH) ? 1.f : 0.f;                              \
            s.y = (m1 >= LIF_THRESH) ? 1.f : 0.f;                              \
            s.z = (m2 >= LIF_THRESH) ? 1.f : 0.f;                              \
            s.w = (m3 >= LIF_THRESH) ? 1.f : 0.f;                              \
            m0 = (m0 >= LIF_THRESH) ? 0.f : m0;                                \
            m1 = (m1 >= LIF_THRESH) ? 0.f : m1;                                \
            m2 = (m2 >= LIF_THRESH) ? 0.f : m2;                                \
            m3 = (m3 >= LIF_THRESH) ? 0.f : m3;                                \
            __builtin_nontemporal_store(s, &out[(size_t)t * n4 + c]);          \
        }                                                                      \
    }

    STEP(0, bufA, bufB, 0)
    STEP(1, bufB, bufA, 0)
    STEP(2, bufA, bufB, 0)
    STEP(3, bufB, bufA, 0)
    STEP(4, bufA, bufB, 0)
    STEP(5, bufB, bufA, 0)
    STEP(6, bufA, bufB, 0)
    STEP(7, bufB, bufA, 1)
#undef STEP
}

extern "C" void kernel_launch(void* const* d_in, const int* in_sizes, int n_in,
                              void* d_out, int out_size, void* d_ws, size_t ws_size,
                              hipStream_t stream) {
    const v4f* x = (const v4f*)d_in[0];
    v4f* out = (v4f*)d_out;

    long long total = in_sizes[0];
    int n = (int)(total / LIF_T);   // 4,194,304 floats per timestep
    int n4 = n / 4;                 // 1,048,576 v4f columns per timestep

    dim3 block(BLOCK);
    dim3 grid(n4 / (BLOCK * JITER));   // 512 blocks -> 2/CU, 8 waves/CU
    lif_kernel<<<grid, block, 0, stream>>>(x, out, n4);
}

// Round 7
// 225.691 us; speedup vs baseline: 1.0584x; 1.0035x over previous
//
#include <hip/hip_runtime.h>

// LIF scan, T=8, N=4M fp32. 268 MB logical (134 R + 134 W). Bench = 2x 512MiB
// harness poison fills (~160 us @ 6.6 TB/s, uncontrollable) + kernel ~63 us
// (4.2 TB/s effective). FINAL: reverted to the proven-best R9 structure.
//
// Falsification ledger (R1-R15), all on this trace:
//   cached reads:       2.2-2.4 TB/s (R1-R4 regs; R13 LDS-DMA). R13's
//                       FETCH=67MB showed 50% L3 read-hit yet SLOWER ->
//                       allocate PATH is the cap, not HBM bytes. Structural:
//                       t-streams 16MiB apart (4x XCD-L2 span).
//   NT reads:           3.4 (R5) -> 4.2 TB/s with 8-chunk blocking (R9).
//   burst depth:        neutral (R6).      store policy:  neutral (R8).
//   TLB chunking:       neutral (R9 vs prior).
//   stream geometry:    neutral (R10/R11: wave<->t LDS-DMA, 1 sequential
//                       stream/wave, counted vmcnt -- ties at 4.2).
//   MLP 64->256 KB/CU:  neutral (R14: 16 waves/CU, depth-3).
//   L2 scope bypass:    neutral (R15: inline-asm global_load_dwordx4 sc1 nt).
// Three unrelated structures tie at 4.2 TB/s => that is the empirical ceiling
// for this op's traffic shape (16 concurrent 16MiB-separated R/W region
// streams); the 6.29 TB/s single-pair copy model does not transfer.
// Lesson (R12): counted vmcnt windows may only count LOADS -- load/store
// vmcnt retirement ordering is not guaranteed (post-timing race otherwise).

#define LIF_THRESH 0.5f
#define LIF_BETA   0.25f
#define LIF_T      8
#define BLOCK      256
#define JITER      8

typedef float v4f __attribute__((ext_vector_type(4)));

__global__ __launch_bounds__(BLOCK) void lif_kernel(const v4f* __restrict__ x,
                                                    v4f* __restrict__ out,
                                                    int n4) {
    // Block b owns contiguous columns [b*BLOCK*JITER, (b+1)*BLOCK*JITER).
    const int base = blockIdx.x * (BLOCK * JITER) + threadIdx.x;

    v4f cur[LIF_T], nxt[LIF_T];

    // Prologue: chunk 0 loads (nt: read-once streaming, the R5 win).
#pragma unroll
    for (int t = 0; t < LIF_T; ++t)
        cur[t] = __builtin_nontemporal_load(&x[(size_t)t * n4 + base]);

#pragma unroll
    for (int j = 0; j < JITER; ++j) {
        const int c = base + j * BLOCK;

        // Prefetch chunk j+1 BEFORE consuming chunk j: independent loads the
        // compiler can hoist above the compute/stores below -> >=8 outstanding
        // per wave even at 8 waves/CU.
        if (j + 1 < JITER) {
            const int cn = c + BLOCK;
#pragma unroll
            for (int t = 0; t < LIF_T; ++t)
                nxt[t] = __builtin_nontemporal_load(&x[(size_t)t * n4 + cn]);
        }

        float m0 = 0.f, m1 = 0.f, m2 = 0.f, m3 = 0.f;
#pragma unroll
        for (int t = 0; t < LIF_T; ++t) {
            v4f xt = cur[t];
            m0 = m0 * LIF_BETA + xt.x;
            m1 = m1 * LIF_BETA + xt.y;
            m2 = m2 * LIF_BETA + xt.z;
            m3 = m3 * LIF_BETA + xt.w;

            v4f s;
            s.x = (m0 >= LIF_THRESH) ? 1.f : 0.f;
            s.y = (m1 >= LIF_THRESH) ? 1.f : 0.f;
            s.z = (m2 >= LIF_THRESH) ? 1.f : 0.f;
            s.w = (m3 >= LIF_THRESH) ? 1.f : 0.f;

            m0 = (m0 >= LIF_THRESH) ? 0.f : m0;
            m1 = (m1 >= LIF_THRESH) ? 0.f : m1;
            m2 = (m2 >= LIF_THRESH) ? 0.f : m2;
            m3 = (m3 >= LIF_THRESH) ? 0.f : m3;

            __builtin_nontemporal_store(s, &out[(size_t)t * n4 + c]);
        }

        // Rotate buffers (SSA copies, free after full unroll).
        if (j + 1 < JITER) {
#pragma unroll
            for (int t = 0; t < LIF_T; ++t) cur[t] = nxt[t];
        }
    }
}

extern "C" void kernel_launch(void* const* d_in, const int* in_sizes, int n_in,
                              void* d_out, int out_size, void* d_ws, size_t ws_size,
                              hipStream_t stream) {
    const v4f* x = (const v4f*)d_in[0];
    v4f* out = (v4f*)d_out;

    long long total = in_sizes[0];
    int n = (int)(total / LIF_T);   // 4,194,304 floats per timestep
    int n4 = n / 4;                 // 1,048,576 float4 columns per timestep

    dim3 block(BLOCK);
    dim3 grid(n4 / (BLOCK * JITER));   // 512 blocks -> 2 per CU, 8 waves/CU
    lif_kernel<<<grid, block, 0, stream>>>(x, out, n4);
}